// Round 3
// baseline (418.902 us; speedup 1.0000x reference)
//
#include <hip/hip_runtime.h>
#include <math.h>

// Problem constants
#define BB 512
#define TT 2048
#define NTOT (512LL * 2048LL * 16LL)   // 16,777,216 elements
#define ROW4 8192                      // float4s per [T*A] row
#define GAMMA 0.99f
#define GLAM  0.9405f                  // gamma * lam
#define ENTC  1.4189385332046727f      // 0.5 + 0.5*log(2*pi)
#define RDY   1u                       // != 0xAAAAAAAA poison

__device__ __forceinline__ float obj1(float x, float m, float s,
                                      float om, float os, float ad)
{
    float rs  = __builtin_amdgcn_rcpf(s);
    float ros = __builtin_amdgcn_rcpf(os);
    float z   = (x - m) * rs;
    float zo  = (x - om) * ros;
    float d   = 0.5f * (zo * zo - z * z);
    float ratio = os * rs * __expf(d);
    return fminf(ad * ratio, ad * 0.8f);   // faithful clip bug: clipped == 0.8
}

// One persistent block per batch row. 512 blocks, 256 threads.
// __launch_bounds__(256,2) -> >=2 blocks/CU capacity -> all 512 co-resident,
// so the flag-based grid sync cannot deadlock (G16: device-scope atomics).
__global__ __launch_bounds__(256, 2) void fused_kernel(
    const float* __restrict__ rewards, const float* __restrict__ vout,
    const int*   __restrict__ dones,
    const float* __restrict__ mu,     const float* __restrict__ sigma,
    const float* __restrict__ old_mu, const float* __restrict__ old_sigma,
    const float* __restrict__ actions,
    float* __restrict__ out,
    double*   __restrict__ partials,   // [BB]
    unsigned* __restrict__ flags,      // [BB], poisoned 0xAAAAAAAA each launch
    float*    __restrict__ meanF,
    unsigned* __restrict__ meanFlag)
{
    const int b   = blockIdx.x;
    const int tid = threadIdx.x;
    const int lane = tid & 63, wave = tid >> 6;

    __shared__ float  advLDS[TT];      // 8 KB: this row's advantages
    __shared__ double redD[4];
    __shared__ float  wA[4], wB[4];
    __shared__ float  meanSh;

    // ---------------- Phase 1: GAE affine scan for row b -> advLDS ----------
    {
        const float* rw = rewards + (size_t)b * TT;
        const float* V  = vout    + (size_t)b * (TT + 1);
        const int*   dn = dones   + (size_t)b * TT;
        const int tb = (TT - 8) - 8 * tid;   // this thread's t-range [tb, tb+8)

        const float4 r0 = ((const float4*)(rw + tb))[0];
        const float4 r1 = ((const float4*)(rw + tb))[1];
        const float4 v0 = ((const float4*)(V  + tb))[0];
        const float4 v1 = ((const float4*)(V  + tb))[1];
        const float  v8 = V[tb + 8];
        const int4   d0 = ((const int4*)(dn + tb))[0];
        const int4   d1 = ((const int4*)(dn + tb))[1];
        const int    d8 = (tid > 0) ? dn[tb + 8] : 0;   // OOB guard (u==0 case)

        float r_[8] = {r0.x,r0.y,r0.z,r0.w,r1.x,r1.y,r1.z,r1.w};
        float v_[9] = {v0.x,v0.y,v0.z,v0.w,v1.x,v1.y,v1.z,v1.w,v8};
        int   d_[9] = {d0.x,d0.y,d0.z,d0.w,d1.x,d1.y,d1.z,d1.w,d8};

        // u = 8*tid + k (reversed time), y_u = a_u*y_{u-1} + b_u
        float ak[8], bk[8];
        float SA = 1.f, SB = 0.f;      // segment composite (earliest-first)
        #pragma unroll
        for (int k = 0; k < 8; ++k) {
            const int j = 7 - k;       // t = tb + j
            float au, bu;
            if (tid == 0 && k == 0) { au = 0.f; bu = 0.f; }   // u == 0
            else {
                bu = r_[j] + GAMMA * v_[j + 1] - v_[j];
                au = GLAM * (1.f - (float)d_[j + 1]);
            }
            ak[k] = au; bk[k] = bu;
            SB = au * SB + bu;
            SA = au * SA;
        }

        #pragma unroll
        for (int off = 1; off < 64; off <<= 1) {
            float pA = __shfl_up(SA, off, 64);
            float pB = __shfl_up(SB, off, 64);
            if (lane >= off) { SB = SA * pB + SB; SA = SA * pA; }
        }
        if (lane == 63) { wA[wave] = SA; wB[wave] = SB; }
        __syncthreads();
        float PA = 1.f, PB = 0.f;
        for (int w = 0; w < wave; ++w) {
            float aw = wA[w], bw = wB[w];
            PB = aw * PB + bw; PA = aw * PA;
        }
        float EA = __shfl_up(SA, 1, 64), EB = __shfl_up(SB, 1, 64);
        if (lane == 0) { EA = 1.f; EB = 0.f; }
        float x = EA * PB + EB;        // carry into my segment
        #pragma unroll
        for (int k = 0; k < 8; ++k) {
            x = ak[k] * x + bk[k];
            advLDS[tb + 7 - k] = x;
        }
    }
    __syncthreads();

    // ---------------- Phase 2: obj partial sum over row b -------------------
    const size_t base4 = (size_t)b * ROW4;
    const float4* m4  = (const float4*)mu        + base4;
    const float4* s4  = (const float4*)sigma     + base4;
    const float4* om4 = (const float4*)old_mu    + base4;
    const float4* os4 = (const float4*)old_sigma + base4;
    const float4* x4  = (const float4*)actions   + base4;

    double lsum = 0.0;
    #pragma unroll 2
    for (int k = 0; k < 32; ++k) {
        const int v = k * 256 + tid;
        float4 m  = m4[v];
        float4 s  = s4[v];
        float4 om = om4[v];
        float4 os = os4[v];
        float4 xx = x4[v];
        float  ad = advLDS[v >> 2];
        float o0 = obj1(xx.x, m.x, s.x, om.x, os.x, ad);
        float o1 = obj1(xx.y, m.y, s.y, om.y, os.y, ad);
        float o2 = obj1(xx.z, m.z, s.z, om.z, os.z, ad);
        float o3 = obj1(xx.w, m.w, s.w, om.w, os.w, ad);
        lsum += (double)o0 + (double)o1 + (double)o2 + (double)o3;
    }
    #pragma unroll
    for (int off = 32; off > 0; off >>= 1)
        lsum += __shfl_down(lsum, off, 64);
    if (lane == 0) redD[wave] = lsum;
    __syncthreads();
    if (tid == 0) {
        double bs = redD[0] + redD[1] + redD[2] + redD[3];
        __hip_atomic_store(&partials[b], bs, __ATOMIC_RELAXED, __HIP_MEMORY_SCOPE_AGENT);
        __threadfence();
        __hip_atomic_store(&flags[b], RDY, __ATOMIC_RELEASE, __HIP_MEMORY_SCOPE_AGENT);
    }

    // ---------------- Block 0: reduce partials -> mean ----------------------
    if (b == 0) {
        for (int i = tid; i < BB; i += 256) {
            while (__hip_atomic_load(&flags[i], __ATOMIC_ACQUIRE,
                                     __HIP_MEMORY_SCOPE_AGENT) != RDY)
                __builtin_amdgcn_s_sleep(16);
        }
        __syncthreads();   // all 512 flags observed; also orders redD reuse
        double s = __hip_atomic_load(&partials[tid],       __ATOMIC_RELAXED, __HIP_MEMORY_SCOPE_AGENT)
                 + __hip_atomic_load(&partials[tid + 256], __ATOMIC_RELAXED, __HIP_MEMORY_SCOPE_AGENT);
        #pragma unroll
        for (int off = 32; off > 0; off >>= 1)
            s += __shfl_down(s, off, 64);
        if (lane == 0) redD[wave] = s;
        __syncthreads();
        if (tid == 0) {
            double total = redD[0] + redD[1] + redD[2] + redD[3];
            float mn = (float)(total / (double)NTOT);
            __hip_atomic_store(meanF, mn, __ATOMIC_RELAXED, __HIP_MEMORY_SCOPE_AGENT);
            __threadfence();
            __hip_atomic_store(meanFlag, RDY, __ATOMIC_RELEASE, __HIP_MEMORY_SCOPE_AGENT);
        }
    }

    // ---------------- All blocks: wait for mean -----------------------------
    if (tid == 0) {
        while (__hip_atomic_load(meanFlag, __ATOMIC_ACQUIRE,
                                 __HIP_MEMORY_SCOPE_AGENT) != RDY)
            __builtin_amdgcn_s_sleep(32);
        meanSh = __hip_atomic_load(meanF, __ATOMIC_RELAXED, __HIP_MEMORY_SCOPE_AGENT);
    }
    __syncthreads();
    const float mean = meanSh;

    // ---------------- Phase 3: out row b = mean + log(sigma) + ENTC ---------
    // Reverse traversal: tail of the phase-2 stream is the cache-warm part.
    float4* o4 = (float4*)out + base4;
    #pragma unroll 2
    for (int k = 31; k >= 0; --k) {
        const int v = k * 256 + tid;
        float4 s = s4[v];
        float4 o;
        o.x = mean + (__logf(s.x) + ENTC);
        o.y = mean + (__logf(s.y) + ENTC);
        o.z = mean + (__logf(s.z) + ENTC);
        o.w = mean + (__logf(s.w) + ENTC);
        o4[v] = o;
    }
}

// ---------------------------------------------------------------------------
extern "C" void kernel_launch(void* const* d_in, const int* in_sizes, int n_in,
                              void* d_out, int out_size, void* d_ws, size_t ws_size,
                              hipStream_t stream) {
    const float* rewards   = (const float*)d_in[0];   // [B,T]
    const float* critic    = (const float*)d_in[1];   // [B,T+1]
    const float* mu        = (const float*)d_in[2];   // [B,T,A]
    const float* sigma     = (const float*)d_in[3];
    const float* old_mu    = (const float*)d_in[4];
    const float* old_sigma = (const float*)d_in[5];
    const float* actions   = (const float*)d_in[6];
    const int*   dones     = (const int*)d_in[7];     // [B,T]
    float* out = (float*)d_out;

    char* ws = (char*)d_ws;                 // poisoned 0xAA before every launch
    double*   partials = (double*)ws;                 // 4 KB
    unsigned* flags    = (unsigned*)(ws + 4096);      // 2 KB
    float*    meanF    = (float*)(ws + 8192);
    unsigned* meanFlag = (unsigned*)(ws + 8196);

    fused_kernel<<<BB, 256, 0, stream>>>(rewards, critic, dones,
                                         mu, sigma, old_mu, old_sigma, actions,
                                         out, partials, flags, meanF, meanFlag);
}

// Round 4
// 352.961 us; speedup vs baseline: 1.1868x; 1.1868x over previous
//
#include <hip/hip_runtime.h>
#include <math.h>

// Problem constants
#define BB 512
#define TT 2048
#define NTOT (512LL * 2048LL * 16LL)   // 16,777,216 elements
#define NV4  (NTOT / 4)                // 4,194,304 float4s
#define NB2  16384                     // blocks for obj/out (1 float4/thread)
#define GAMMA 0.99f
#define GLAM  0.9405f                  // gamma * lam
#define ENTC  1.4189385332046727f      // 0.5 + 0.5*log(2*pi)

// ---------------------------------------------------------------------------
// K1: GAE via parallel affine scan. One block (256 threads) per batch row.
// (verified absmax 0.0 in R2/R3)
// ---------------------------------------------------------------------------
__global__ __launch_bounds__(256) void gae_kernel(
    const float* __restrict__ rewards, const float* __restrict__ vout,
    const int* __restrict__ dones, float* __restrict__ adv)
{
    const int b   = blockIdx.x;
    const int tid = threadIdx.x;
    const float* rw = rewards + (size_t)b * TT;
    const float* V  = vout    + (size_t)b * (TT + 1);
    const int*   dn = dones   + (size_t)b * TT;
    float*       av = adv     + (size_t)b * TT;

    const int tb = (TT - 8) - 8 * tid;   // this thread's t-range [tb, tb+8)

    const float4 r0 = ((const float4*)(rw + tb))[0];
    const float4 r1 = ((const float4*)(rw + tb))[1];
    const float4 v0 = ((const float4*)(V  + tb))[0];
    const float4 v1 = ((const float4*)(V  + tb))[1];
    const float  v8 = V[tb + 8];
    const int4   d0 = ((const int4*)(dn + tb))[0];
    const int4   d1 = ((const int4*)(dn + tb))[1];
    const int    d8 = (tid > 0) ? dn[tb + 8] : 0;   // OOB guard (u==0 case)

    float r_[8] = {r0.x,r0.y,r0.z,r0.w,r1.x,r1.y,r1.z,r1.w};
    float v_[9] = {v0.x,v0.y,v0.z,v0.w,v1.x,v1.y,v1.z,v1.w,v8};
    int   d_[9] = {d0.x,d0.y,d0.z,d0.w,d1.x,d1.y,d1.z,d1.w,d8};

    float ak[8], bk[8];
    float SA = 1.f, SB = 0.f;          // segment composite (earliest-first)
    #pragma unroll
    for (int k = 0; k < 8; ++k) {
        const int j = 7 - k;           // t = tb + j, u = 8*tid + k
        float au, bu;
        if (tid == 0 && k == 0) { au = 0.f; bu = 0.f; }   // u == 0
        else {
            bu = r_[j] + GAMMA * v_[j + 1] - v_[j];
            au = GLAM * (1.f - (float)d_[j + 1]);
        }
        ak[k] = au; bk[k] = bu;
        SB = au * SB + bu;
        SA = au * SA;
    }

    const int lane = tid & 63;
    const int wave = tid >> 6;

    #pragma unroll
    for (int off = 1; off < 64; off <<= 1) {
        float pA = __shfl_up(SA, off, 64);
        float pB = __shfl_up(SB, off, 64);
        if (lane >= off) { SB = SA * pB + SB; SA = SA * pA; }
    }

    __shared__ float wA[4], wB[4];
    if (lane == 63) { wA[wave] = SA; wB[wave] = SB; }
    __syncthreads();

    float PA = 1.f, PB = 0.f;
    for (int w = 0; w < wave; ++w) {
        float aw = wA[w], bw = wB[w];
        PB = aw * PB + bw;
        PA = aw * PA;
    }

    float EA = __shfl_up(SA, 1, 64);
    float EB = __shfl_up(SB, 1, 64);
    if (lane == 0) { EA = 1.f; EB = 0.f; }

    float x = EA * PB + EB;            // carry into my segment
    float xv[8];
    #pragma unroll
    for (int k = 0; k < 8; ++k) {
        x = ak[k] * x + bk[k];
        xv[k] = x;
    }
    float4 o0 = {xv[7], xv[6], xv[5], xv[4]};   // t = tb..tb+3
    float4 o1 = {xv[3], xv[2], xv[1], xv[0]};   // t = tb+4..tb+7
    ((float4*)(av + tb))[0] = o0;
    ((float4*)(av + tb))[1] = o1;
}

// ---------------------------------------------------------------------------
// K2: PPO objective partial sums — pure-TLP shape: ONE float4 per thread,
// 16384 blocks. Minimal registers, full occupancy, copy-probe-like.
// clipped == 0.8 (faithful clip bug).
// ---------------------------------------------------------------------------
__device__ __forceinline__ float obj1(float x, float m, float s,
                                      float om, float os, float ad)
{
    float rs  = __builtin_amdgcn_rcpf(s);
    float ros = __builtin_amdgcn_rcpf(os);
    float z   = (x - m) * rs;
    float zo  = (x - om) * ros;
    float d   = 0.5f * (zo * zo - z * z);
    float ratio = os * rs * __expf(d);
    return fminf(ad * ratio, ad * 0.8f);
}

__global__ __launch_bounds__(256) void obj_kernel(
    const float* __restrict__ mu, const float* __restrict__ sigma,
    const float* __restrict__ old_mu, const float* __restrict__ old_sigma,
    const float* __restrict__ actions, const float* __restrict__ adv,
    double* __restrict__ partials)
{
    const int tid = threadIdx.x;
    const size_t v = (size_t)blockIdx.x * 256 + tid;   // float4 index

    float4 m  = ((const float4*)mu)[v];
    float4 s  = ((const float4*)sigma)[v];
    float4 om = ((const float4*)old_mu)[v];
    float4 os = ((const float4*)old_sigma)[v];
    float4 x  = ((const float4*)actions)[v];
    float  ad = adv[v >> 2];

    float o = obj1(x.x, m.x, s.x, om.x, os.x, ad)
            + obj1(x.y, m.y, s.y, om.y, os.y, ad)
            + obj1(x.z, m.z, s.z, om.z, os.z, ad)
            + obj1(x.w, m.w, s.w, om.w, os.w, ad);
    double lsum = (double)o;

    #pragma unroll
    for (int off = 32; off > 0; off >>= 1)
        lsum += __shfl_down(lsum, off, 64);

    __shared__ double wsum[4];
    const int lane = tid & 63, wave = tid >> 6;
    if (lane == 0) wsum[wave] = lsum;
    __syncthreads();
    if (tid == 0)
        partials[blockIdx.x] = wsum[0] + wsum[1] + wsum[2] + wsum[3];
}

// ---------------------------------------------------------------------------
// K2b: reduce NB2 partials -> mean (single block, 256 threads)
// ---------------------------------------------------------------------------
__global__ __launch_bounds__(256) void reduce_kernel(
    const double* __restrict__ partials, float* __restrict__ meanOut)
{
    const int tid = threadIdx.x;
    double s = 0.0;
    for (int i = tid; i < NB2; i += 256) s += partials[i];
    #pragma unroll
    for (int off = 32; off > 0; off >>= 1)
        s += __shfl_down(s, off, 64);
    __shared__ double wsum[4];
    const int lane = tid & 63, wave = tid >> 6;
    if (lane == 0) wsum[wave] = s;
    __syncthreads();
    if (tid == 0) {
        double total = wsum[0] + wsum[1] + wsum[2] + wsum[3];
        meanOut[0] = (float)(total / (double)NTOT);
    }
}

// ---------------------------------------------------------------------------
// K3: out[i] = mean + log(sigma[i]) + ENTC. One float4 per thread, reversed
// block order so the L3-warm tail of sigma (last touched by K2) is read first.
// ---------------------------------------------------------------------------
__global__ __launch_bounds__(256) void out_kernel(
    const float* __restrict__ sigma, const float* __restrict__ meanPtr,
    float* __restrict__ out)
{
    const size_t v = (size_t)(NB2 - 1 - blockIdx.x) * 256 + threadIdx.x;
    const float mean = meanPtr[0];
    float4 s = ((const float4*)sigma)[v];
    float4 o;
    o.x = mean + (__logf(s.x) + ENTC);
    o.y = mean + (__logf(s.y) + ENTC);
    o.z = mean + (__logf(s.z) + ENTC);
    o.w = mean + (__logf(s.w) + ENTC);
    ((float4*)out)[v] = o;
}

// ---------------------------------------------------------------------------
extern "C" void kernel_launch(void* const* d_in, const int* in_sizes, int n_in,
                              void* d_out, int out_size, void* d_ws, size_t ws_size,
                              hipStream_t stream) {
    const float* rewards   = (const float*)d_in[0];   // [B,T]
    const float* critic    = (const float*)d_in[1];   // [B,T+1]
    const float* mu        = (const float*)d_in[2];   // [B,T,A]
    const float* sigma     = (const float*)d_in[3];
    const float* old_mu    = (const float*)d_in[4];
    const float* old_sigma = (const float*)d_in[5];
    const float* actions   = (const float*)d_in[6];
    const int*   dones     = (const int*)d_in[7];     // [B,T]
    float* out = (float*)d_out;

    char* ws = (char*)d_ws;
    float*  meanPtr  = (float*)ws;                    // 4 B
    double* partials = (double*)(ws + 1024);          // 128 KB (NB2 doubles)
    float*  adv      = (float*)(ws + 1024 + 131072);  // 4 MB (B*T floats)

    gae_kernel<<<BB, 256, 0, stream>>>(rewards, critic, dones, adv);
    obj_kernel<<<NB2, 256, 0, stream>>>(mu, sigma, old_mu, old_sigma,
                                        actions, adv, partials);
    reduce_kernel<<<1, 256, 0, stream>>>(partials, meanPtr);
    out_kernel<<<NB2, 256, 0, stream>>>(sigma, meanPtr, out);
}